// Round 5
// baseline (13392.075 us; speedup 1.0000x reference)
//
#include <hip/hip_runtime.h>
#include <hip/hip_bf16.h>

// LlamaSdpaAttention: B=2, S=2048, HIDDEN=4096, NH=32, NKV=8, D=128, theta=5e5
// Round 5: inputs proven fp32 (round-4 NaN bisect). Output now written fp32
// (reference's literal output dtype). Compute pipeline in bf16 MFMA.
// conv(fp32->bf16) -> gemm(qkv) -> rope -> naive attn -> gemm(out, fp32).

typedef __attribute__((ext_vector_type(8))) short bf16x8;   // 8 bf16 = 4 VGPRs
typedef __attribute__((ext_vector_type(4))) float floatx4;  // MFMA C/D frag
using bf16 = __hip_bfloat16;

#define LOG2E 1.44269504088896340736f

__device__ __forceinline__ void store_out(bf16* p, float v) { *p = __float2bfloat16(v); }
__device__ __forceinline__ void store_out(float* p, float v) { *p = v; }

// ---------------------------------------------------------------------------
// Convert unknown-dtype (fp32 or bf16) array to bf16. Detector: for packed
// bf16 the low-half exponent field of each word is in the plausible-normal
// range; for fp32 those bits are mid-mantissa (pseudo-random). Uniform branch.
// ---------------------------------------------------------------------------
__global__ __launch_bounds__(256) void conv_to_bf16(const void* __restrict__ src,
                                                    bf16* __restrict__ dst,
                                                    size_t n)
{
  const unsigned* u32 = (const unsigned*)src;
  int score = 0;
#pragma unroll
  for (int i = 0; i < 16; i++) {
    unsigned e = (u32[i] >> 7) & 0xFF;  // low-half bf16 exponent field
    score += (e >= 0x6E && e <= 0x84) ? 1 : 0;
  }
  const bool is_bf16 = score >= 12;
  size_t i = ((size_t)blockIdx.x * 256 + threadIdx.x) * 8;
  if (i >= n) return;
  if (is_bf16) {
    *(bf16x8*)(dst + i) = *(const bf16x8*)((const bf16*)src + i);
  } else {
    const float* f = (const float*)src;
    bf16 tmp[8];
#pragma unroll
    for (int j = 0; j < 8; j++) tmp[j] = __float2bfloat16(f[i + j]);
    *(bf16x8*)(dst + i) = *(bf16x8*)tmp;
  }
}

// ---------------------------------------------------------------------------
// GEMM: C[M,N] = A[M,K] @ B[N,K]^T, bf16 in, fp32 accumulate, OT out.
// 128x128 tile, BK=64, 256 threads (4 waves, each 64x64), 16x16x32 bf16 MFMA.
// ---------------------------------------------------------------------------
template <typename OT>
__global__ __launch_bounds__(256) void gemm_bt(const bf16* __restrict__ A,
                                               const bf16* __restrict__ B,
                                               OT* __restrict__ C,
                                               int M, int N, int K)
{
  __shared__ bf16 As[128 * 64];
  __shared__ bf16 Bs[128 * 64];
  const int tid  = threadIdx.x;
  const int wave = tid >> 6, lane = tid & 63;
  const int quad = lane >> 4, m16 = lane & 15;
  const int m0 = blockIdx.y * 128, n0 = blockIdx.x * 128;
  const int wr = (wave >> 1) * 64, wc = (wave & 1) * 64;

  floatx4 acc[4][4];
#pragma unroll
  for (int i = 0; i < 4; i++)
#pragma unroll
    for (int j = 0; j < 4; j++) acc[i][j] = (floatx4){0.f, 0.f, 0.f, 0.f};

  const int srow = tid >> 3;        // 0..31  (+32 per step)
  const int scol = (tid & 7) * 8;   // 0..56

  for (int kt = 0; kt < K; kt += 64) {
    bf16x8 sa[4], sb[4];
#pragma unroll
    for (int i = 0; i < 4; i++) {
      sa[i] = *(const bf16x8*)(A + (size_t)(m0 + srow + i * 32) * K + kt + scol);
      sb[i] = *(const bf16x8*)(B + (size_t)(n0 + srow + i * 32) * K + kt + scol);
    }
#pragma unroll
    for (int i = 0; i < 4; i++) {
      *(bf16x8*)(As + (srow + i * 32) * 64 + scol) = sa[i];
      *(bf16x8*)(Bs + (srow + i * 32) * 64 + scol) = sb[i];
    }
    __syncthreads();
#pragma unroll
    for (int kk = 0; kk < 2; ++kk) {
      bf16x8 a[4], b[4];
#pragma unroll
      for (int i = 0; i < 4; i++)
        a[i] = *(const bf16x8*)(As + (wr + i * 16 + m16) * 64 + kk * 32 + quad * 8);
#pragma unroll
      for (int j = 0; j < 4; j++)
        b[j] = *(const bf16x8*)(Bs + (wc + j * 16 + m16) * 64 + kk * 32 + quad * 8);
#pragma unroll
      for (int i = 0; i < 4; i++)
#pragma unroll
        for (int j = 0; j < 4; j++)
          acc[i][j] = __builtin_amdgcn_mfma_f32_16x16x32_bf16(a[i], b[j], acc[i][j], 0, 0, 0);
    }
    __syncthreads();
  }

  // C/D layout: col = lane&15, row = quad*4 + reg  [verified m89/m91]
  const int row = m0 + wr + quad * 4;
  const int col = n0 + wc + m16;
#pragma unroll
  for (int i = 0; i < 4; i++)
#pragma unroll
    for (int j = 0; j < 4; j++)
#pragma unroll
      for (int r = 0; r < 4; r++)
        store_out(&C[(size_t)(row + i * 16 + r) * N + col + j * 16], acc[i][j][r]);
}

// ---------------------------------------------------------------------------
// RoPE in place on q [4096 x 4096] and k [4096 x 1024].
// position_ids auto-detects int64 vs int32 (pos32[1]==0 <=> int64: arange).
// ---------------------------------------------------------------------------
__global__ __launch_bounds__(256) void rope_kernel(bf16* __restrict__ q,
                                                   bf16* __restrict__ k,
                                                   const int* __restrict__ pos)
{
  int idx = blockIdx.x * 256 + threadIdx.x;  // 4096 * 2048 threads
  int row = idx >> 11;
  int p   = idx & 2047;
  int h   = p >> 6, j = p & 63;
  const bool p64 = (pos[1] == 0);
  float t = (float)(p64 ? pos[2 * row] : pos[row]);
  // inv_freq = theta^(-j/64) ; log2(500000) = 18.9315685693
  float inv_freq = exp2f(-(float)j * (18.9315685693241741f / 64.0f));
  float fr = t * inv_freq;
  float s, c;
  sincosf(fr, &s, &c);

  size_t base = (size_t)row * 4096 + h * 128 + j;
  float a  = __bfloat162float(q[base]);
  float b2 = __bfloat162float(q[base + 64]);
  q[base]      = __float2bfloat16(a * c - b2 * s);
  q[base + 64] = __float2bfloat16(b2 * c + a * s);
  if (h < 8) {
    size_t kb = (size_t)row * 1024 + h * 128 + j;
    a  = __bfloat162float(k[kb]);
    b2 = __bfloat162float(k[kb + 64]);
    k[kb]      = __float2bfloat16(a * c - b2 * s);
    k[kb + 64] = __float2bfloat16(b2 * c + a * s);
  }
}

// ---------------------------------------------------------------------------
// Naive attention: one block per (qrow, head, batch). Causality via loop
// bounds (keys 0..qrow). Scores in LDS fp32. Exactly mirrors the reference.
// ---------------------------------------------------------------------------
__global__ __launch_bounds__(256) void attn_naive(const bf16* __restrict__ q,
                                                  const bf16* __restrict__ k,
                                                  const bf16* __restrict__ v,
                                                  bf16* __restrict__ o)
{
  __shared__ float sc[2048];
  __shared__ float red[256];
  __shared__ float qs[128];
  const int qrow = blockIdx.x, h = blockIdx.y, b = blockIdx.z, g = h >> 2;
  const int tid = threadIdx.x;
  const int n = qrow + 1;  // number of visible keys

  if (tid < 128)
    qs[tid] = __bfloat162float(q[(size_t)(b * 2048 + qrow) * 4096 + h * 128 + tid]);
  __syncthreads();

  const float scale = 0.08838834764831843f;  // 1/sqrt(128)
  float lmax = -3.0e38f;
  for (int kk = tid; kk < n; kk += 256) {
    const bf16* kr = k + (size_t)(b * 2048 + kk) * 1024 + g * 128;
    float dot = 0.f;
#pragma unroll
    for (int d = 0; d < 128; d += 8) {
      bf16x8 kv8 = *(const bf16x8*)(kr + d);
      const bf16* ke = (const bf16*)&kv8;
      float4 qa = *(const float4*)(qs + d);
      float4 qb2 = *(const float4*)(qs + d + 4);
      dot += qa.x * __bfloat162float(ke[0]) + qa.y * __bfloat162float(ke[1]) +
             qa.z * __bfloat162float(ke[2]) + qa.w * __bfloat162float(ke[3]) +
             qb2.x * __bfloat162float(ke[4]) + qb2.y * __bfloat162float(ke[5]) +
             qb2.z * __bfloat162float(ke[6]) + qb2.w * __bfloat162float(ke[7]);
    }
    dot *= scale;
    sc[kk] = dot;
    lmax = fmaxf(lmax, dot);
  }
#pragma unroll
  for (int off = 32; off; off >>= 1) lmax = fmaxf(lmax, __shfl_xor(lmax, off));
  if ((tid & 63) == 0) red[tid >> 6] = lmax;
  __syncthreads();
  const float m = fmaxf(fmaxf(red[0], red[1]), fmaxf(red[2], red[3]));

  float ls = 0.f;
  for (int kk = tid; kk < n; kk += 256) {
    float p = exp2f((sc[kk] - m) * LOG2E);
    sc[kk] = p;
    ls += p;
  }
#pragma unroll
  for (int off = 32; off; off >>= 1) ls += __shfl_xor(ls, off);
  __syncthreads();  // m consumed; sc writes visible before PV
  if ((tid & 63) == 0) red[tid >> 6] = ls;
  __syncthreads();
  const float l = red[0] + red[1] + red[2] + red[3];

  const int d = tid & 127, half = tid >> 7;
  float acc = 0.f;
  for (int kk = half; kk < n; kk += 2)
    acc += sc[kk] * __bfloat162float(v[(size_t)(b * 2048 + kk) * 1024 + g * 128 + d]);
  __syncthreads();  // l consumed
  red[tid] = acc;
  __syncthreads();
  if (tid < 128)
    o[(size_t)(b * 2048 + qrow) * 4096 + h * 128 + tid] =
        __float2bfloat16((red[tid] + red[tid + 128]) / l);
}

// ---------------------------------------------------------------------------
extern "C" void kernel_launch(void* const* d_in, const int* in_sizes, int n_in,
                              void* d_out, int out_size, void* d_ws, size_t ws_size,
                              hipStream_t stream)
{
  const int* pos = (const int*)d_in[1];
  float* out = (float*)d_out;  // reference output dtype: fp32

  // Workspace layout (112 MB total):
  char* w = (char*)d_ws;
  bf16* xb = (bf16*)w;               // x  converted  [4096][4096]  32 MB
  bf16* ab = xb;                     // attn output aliases xb (x dead by then)
  bf16* wb = (bf16*)(w + (size_t)32 * 1024 * 1024);  // weight staging 32 MB
  bf16* qb = (bf16*)(w + (size_t)64 * 1024 * 1024);  // q [4096][4096] 32 MB
  bf16* kb = (bf16*)(w + (size_t)96 * 1024 * 1024);  // k [4096][1024]  8 MB
  bf16* vb = (bf16*)(w + (size_t)104 * 1024 * 1024); // v [4096][1024]  8 MB

  const size_t NBIG = (size_t)4096 * 4096;   // 16.7M elts
  const size_t NSML = (size_t)4096 * 1024;   // 4.2M elts
  const int GBIG = (int)(NBIG / 8 / 256);    // 8192 blocks
  const int GSML = (int)(NSML / 8 / 256);    // 2048 blocks

  conv_to_bf16<<<GBIG, 256, 0, stream>>>(d_in[0], xb, NBIG);  // x

  conv_to_bf16<<<GBIG, 256, 0, stream>>>(d_in[2], wb, NBIG);  // wq
  gemm_bt<bf16><<<dim3(32, 32), 256, 0, stream>>>(xb, wb, qb, 4096, 4096, 4096);

  conv_to_bf16<<<GSML, 256, 0, stream>>>(d_in[3], wb, NSML);  // wk
  gemm_bt<bf16><<<dim3(8, 32), 256, 0, stream>>>(xb, wb, kb, 4096, 1024, 4096);

  conv_to_bf16<<<GSML, 256, 0, stream>>>(d_in[4], wb, NSML);  // wv
  gemm_bt<bf16><<<dim3(8, 32), 256, 0, stream>>>(xb, wb, vb, 4096, 1024, 4096);

  rope_kernel<<<32768, 256, 0, stream>>>(qb, kb, pos);

  attn_naive<<<dim3(2048, 32, 2), 256, 0, stream>>>(qb, kb, vb, ab);

  conv_to_bf16<<<GBIG, 256, 0, stream>>>(d_in[5], wb, NBIG);  // wo
  gemm_bt<float><<<dim3(32, 32), 256, 0, stream>>>(ab, wb, out, 4096, 4096, 4096);
}